// Round 17
// baseline (107.611 us; speedup 1.0000x reference)
//
#include <hip/hip_runtime.h>
#include <hip/hip_bf16.h>

// Problem constants
#define B_   4
#define C_   32
#define H_   192
#define W_   192
#define HW_  (H_ * W_)          // 36864
#define EPS_ 1e-5f

#define SCALE_IN  21.640425613334453f   // beta/ln2
#define SCALE_OUT 0.046209812037329687f // ln2/beta

#define SPW 48                  // sP row stride
#define SQW 40                  // sQ row stride

#define NP1 (128 * 576)         // chan * (4 b * 36 tiles * 4 waves)
#define NP2 (32 * 288)          // chan * (4 b * 72 blocks)

typedef float vf2 __attribute__((ext_vector_type(2)));

// bf16 <-> f32 helpers (bit-exact shift load, RNE store)
__device__ __forceinline__ float bf2f(unsigned short u) {
    return __uint_as_float((unsigned int)u << 16);
}
__device__ __forceinline__ unsigned short f2bf(float f) {
    const unsigned int u = __float_as_uint(f);
    return (unsigned short)((u + 0x7fffu + ((u >> 16) & 1u)) >> 16);
}

// ---------------------------------------------------------------------------
// Scratch (module globals; no atomics anywhere).
//  g_cw[0..1151] = 2^(s*wd), [1152..2303] = 2^(s*we)   ((br*C+c)*9+tap)
//  g_Wt[ci*32+o] = Wc[o*128+ci]  (filled by fin1_k)
//  g_stats[0..127] sc1  [128..255] sh1
// ---------------------------------------------------------------------------
__device__ float          g_cw[2304];
__device__ float          g_Wt[4096];
__device__ float          g_stats[256];
__device__ float          g_p1[2 * NP1];
__device__ float          g_p2[2 * NP2];
__device__ __attribute__((aligned(16))) unsigned short g_E[(size_t)4 * B_ * C_ * HW_];  // 37.75 MB
__device__ __attribute__((aligned(16))) unsigned short g_Yb[(size_t)B_ * C_ * HW_];     // 9.44 MB

// ---------------------------------------------------------------------------
// prep: exponentiate morphology weights (wave-uniform s_loads in morph_k)
// ---------------------------------------------------------------------------
__global__ void prep_k(const float* __restrict__ wd, const float* __restrict__ we) {
    for (int i = threadIdx.x; i < 2304; i += 256) {
        const float v = (i < 1152) ? wd[i] : we[i - 1152];
        g_cw[i] = exp2f(SCALE_IN * v);
    }
}

// ---------------------------------------------------------------------------
// One morphology branch (dilate-recip + erode) on a staged 48x48 P tile.
// sP: P = 2^(s*x), halo +-8, out-of-image = 1.0. sQ: Q = 1/dilate-sum.
// 4 cells/thread, float4 LDS ops, all tap indices compile-time via D.
// INT: whole Q window in-image -> skip per-cell bounds select.
// ---------------------------------------------------------------------------
template<int D, bool INT>
__device__ __forceinline__ void morph_branch(int b, int c, int h0, int w0,
                                             int slotbase,
                                             const float* __restrict__ sP,
                                             float* __restrict__ sQ) {
    constexpr int QE    = 32 + 2 * D;
    constexpr int QEG   = (QE + 3) / 4;
    constexpr int UNITS = QE * QEG;
    constexpr int POFF  = 8 - 2 * D;
    constexpr int AB    = POFF & ~3;
    constexpr int OFF   = POFF & 3;
    constexpr int NR    = (OFF + 2 * D + 4 + 3) / 4;
    constexpr int NR3   = (2 * D + 4 + 3) / 4;
    constexpr int br    = D - 1;

    const int tid = threadIdx.x;
    const int cb  = (br * C_ + c) * 9;

    // ---- phase 2: Q = rcp( sum cd * P_taps ); out-of-image cells := 1 ----
    {
        float cd[9];
#pragma unroll
        for (int k = 0; k < 9; k++) cd[k] = g_cw[cb + k];

#pragma unroll
        for (int it = 0; it < 2; ++it) {
            const int unit = tid + it * 256;
            if (unit < UNITS) {
                const int qi = unit / QEG;
                const int qj = (unit - qi * QEG) * 4;
                float a0 = 0.f, a1 = 0.f, a2 = 0.f, a3 = 0.f;
#pragma unroll
                for (int i = 0; i < 3; i++) {
                    const float* rp = &sP[(qi + 8 + (i - 2) * D) * SPW + qj + AB];
                    float buf[NR * 4];
#pragma unroll
                    for (int r = 0; r < NR; r++)
                        *(float4*)&buf[r * 4] = *(const float4*)&rp[r * 4];
#pragma unroll
                    for (int j = 0; j < 3; j++) {
                        const float wgt = cd[i * 3 + j];
                        a0 = fmaf(wgt, buf[OFF + j * D + 0], a0);
                        a1 = fmaf(wgt, buf[OFF + j * D + 1], a1);
                        a2 = fmaf(wgt, buf[OFF + j * D + 2], a2);
                        a3 = fmaf(wgt, buf[OFF + j * D + 3], a3);
                    }
                }
                float q0 = __builtin_amdgcn_rcpf(a0);
                float q1 = __builtin_amdgcn_rcpf(a1);
                float q2 = __builtin_amdgcn_rcpf(a2);
                float q3 = __builtin_amdgcn_rcpf(a3);
                if constexpr (!INT) {
                    const int hq = h0 - D + qi;
                    const int wq = w0 - D + qj;
                    const bool rowo = (hq < 0) || (hq >= H_);
                    q0 = (rowo || (wq + 0 < 0) || (wq + 0 >= W_)) ? 1.0f : q0;
                    q1 = (rowo || (wq + 1 < 0) || (wq + 1 >= W_)) ? 1.0f : q1;
                    q2 = (rowo || (wq + 2 < 0) || (wq + 2 >= W_)) ? 1.0f : q2;
                    q3 = (rowo || (wq + 3 < 0) || (wq + 3 >= W_)) ? 1.0f : q3;
                }
                *(float4*)&sQ[qi * SQW + qj] = make_float4(q0, q1, q2, q3);
            }
        }
    }
    __syncthreads();

    // ---- phase 3: E = -(ln2/beta)*log2( sum ce * Q_taps ), 4 px/thread ----
    {
        float ce[9];
#pragma unroll
        for (int k = 0; k < 9; k++) ce[k] = g_cw[1152 + cb + k];

        const int oi = tid >> 3;
        const int oj = (tid & 7) * 4;
        float t0 = 0.f, t1 = 0.f, t2 = 0.f, t3 = 0.f;
#pragma unroll
        for (int i = 0; i < 3; i++) {
            const float* rq = &sQ[(oi + i * D) * SQW + oj];
            float buf[NR3 * 4];
#pragma unroll
            for (int r = 0; r < NR3; r++)
                *(float4*)&buf[r * 4] = *(const float4*)&rq[r * 4];
#pragma unroll
            for (int j = 0; j < 3; j++) {
                const float wgt = ce[i * 3 + j];
                t0 = fmaf(wgt, buf[j * D + 0], t0);
                t1 = fmaf(wgt, buf[j * D + 1], t1);
                t2 = fmaf(wgt, buf[j * D + 2], t2);
                t3 = fmaf(wgt, buf[j * D + 3], t3);
            }
        }
        const float e0 = -SCALE_OUT * log2f(t0);
        const float e1 = -SCALE_OUT * log2f(t1);
        const float e2 = -SCALE_OUT * log2f(t2);
        const float e3 = -SCALE_OUT * log2f(t3);

        ushort4 r4;
        r4.x = f2bf(e0); r4.y = f2bf(e1); r4.z = f2bf(e2); r4.w = f2bf(e3);
        *(ushort4*)&g_E[(((size_t)br * B_ + b) * C_ + c) * HW_
                        + (size_t)(h0 + oi) * W_ + w0 + oj] = r4;

        float s1 = e0 + e1 + e2 + e3;
        float s2 = e0 * e0 + e1 * e1 + e2 * e2 + e3 * e3;
#pragma unroll
        for (int off = 32; off >= 1; off >>= 1) {
            s1 += __shfl_down(s1, off, 64);
            s2 += __shfl_down(s2, off, 64);
        }
        if ((tid & 63) == 0) {
            const int slot = (br * C_ + c) * 576 + slotbase + (tid >> 6);
            g_p1[slot]       = s1;
            g_p1[NP1 + slot] = s2;
        }
    }
    __syncthreads();
}

// ---------------------------------------------------------------------------
// fused all-branch morphology. grid (36 tiles, 32 c, 4 b), 256 threads.
// Stage is vectorized (float4) for column-interior tiles (tw 1..4).
// ---------------------------------------------------------------------------
__global__ __launch_bounds__(256) void morph_k(const float* __restrict__ x) {
    __shared__ float sP[48 * SPW];
    __shared__ float sQ[40 * SQW];
    const int tile = blockIdx.x;
    const int c    = blockIdx.y;
    const int b    = blockIdx.z;
    const int th   = tile / 6;
    const int tw   = tile - th * 6;
    const int h0   = th * 32, w0 = tw * 32;

    const float* xm = x + (size_t)(b * C_ + c) * HW_;
    if (tw >= 1 && tw <= 4) {
        // fast path: all 48 columns in-image; only row range needs checking
#pragma unroll
        for (int pass = 0; pass < 3; ++pass) {
            const int u = threadIdx.x + pass * 256;
            if (u < 576) {
                const int r  = u / 12;
                const int q4 = (u - r * 12) * 4;
                const int ih = h0 - 8 + r;
                float4 v;
                if (ih >= 0 && ih < H_) {
                    const float4 xv = *(const float4*)&xm[ih * W_ + (w0 - 8 + q4)];
                    v.x = exp2f(SCALE_IN * xv.x);
                    v.y = exp2f(SCALE_IN * xv.y);
                    v.z = exp2f(SCALE_IN * xv.z);
                    v.w = exp2f(SCALE_IN * xv.w);
                } else {
                    v = make_float4(1.f, 1.f, 1.f, 1.f);
                }
                *(float4*)&sP[r * SPW + q4] = v;
            }
        }
    } else {
        // slow path: per-cell clamp + pad-select
        for (int idx = threadIdx.x; idx < 48 * 48; idx += 256) {
            const int r  = idx / 48, q = idx - r * 48;
            const int ih = h0 - 8 + r, iw = w0 - 8 + q;
            const int ihc = min(max(ih, 0), H_ - 1);
            const int iwc = min(max(iw, 0), W_ - 1);
            const float xv = xm[ihc * W_ + iwc];
            const bool inb = (ih == ihc) && (iw == iwc);
            sP[r * SPW + q] = inb ? exp2f(SCALE_IN * xv) : 1.0f;
        }
    }
    __syncthreads();

    const int slotbase = (b * 36 + tile) * 4;
    if (th >= 1 && th <= 4 && tw >= 1 && tw <= 4) {
        morph_branch<1, true>(b, c, h0, w0, slotbase, sP, sQ);
        morph_branch<2, true>(b, c, h0, w0, slotbase, sP, sQ);
        morph_branch<3, true>(b, c, h0, w0, slotbase, sP, sQ);
        morph_branch<4, true>(b, c, h0, w0, slotbase, sP, sQ);
    } else {
        morph_branch<1, false>(b, c, h0, w0, slotbase, sP, sQ);
        morph_branch<2, false>(b, c, h0, w0, slotbase, sP, sQ);
        morph_branch<3, false>(b, c, h0, w0, slotbase, sP, sQ);
        morph_branch<4, false>(b, c, h0, w0, slotbase, sP, sQ);
    }
}

// ---------------------------------------------------------------------------
// finalize BN1 (reduce 576 partials per channel) + Wc transpose. grid = 128
// ---------------------------------------------------------------------------
__global__ __launch_bounds__(256) void fin1_k(const float* __restrict__ gs,
                                              const float* __restrict__ bs,
                                              const float* __restrict__ Wc) {
    const int chan = blockIdx.x;          // input channel ci
    if (threadIdx.x < 32)
        g_Wt[chan * 32 + threadIdx.x] = Wc[(size_t)threadIdx.x * 128 + chan];

    const int base = chan * 576;
    float s1 = 0.0f, s2 = 0.0f;
    for (int i = threadIdx.x; i < 576; i += 256) {
        s1 += g_p1[base + i];
        s2 += g_p1[NP1 + base + i];
    }
#pragma unroll
    for (int off = 32; off >= 1; off >>= 1) {
        s1 += __shfl_down(s1, off, 64);
        s2 += __shfl_down(s2, off, 64);
    }
    __shared__ float l1[4], l2[4];
    const int lane = threadIdx.x & 63;
    const int wv   = threadIdx.x >> 6;
    if (lane == 0) { l1[wv] = s1; l2[wv] = s2; }
    __syncthreads();
    if (threadIdx.x == 0) {
        const float S1 = l1[0] + l1[1] + l1[2] + l1[3];
        const float S2 = l2[0] + l2[1] + l2[2] + l2[3];
        const float N  = (float)(B_ * HW_);
        const float mu = S1 / N;
        const float va = fmaxf(S2 / N - mu * mu, 0.0f);
        const float sc = gs[chan] * rsqrtf(va + EPS_);
        g_stats[chan]       = sc;
        g_stats[128 + chan] = bs[chan] - mu * sc;
    }
}

// ---------------------------------------------------------------------------
// fused BN1+ReLU + 1x1 conv + BN2 partials. grid (72, 2 og, 4 b).
// 2 pixels/thread as packed float2 lanes -> v_pk_fma_f32; 16 outputs/thread.
// Weights/scales wave-uniform (scalar); Y stored bf16.
// ---------------------------------------------------------------------------
__global__ __launch_bounds__(256) void conv_k(void) {
    const int og = blockIdx.y;            // outputs og*16 .. og*16+15
    const int b  = blockIdx.z;
    const int p  = (blockIdx.x * 256 + threadIdx.x) * 2;

    vf2 acc[16];
#pragma unroll
    for (int k = 0; k < 16; k++) acc[k] = (vf2){0.f, 0.f};

#pragma unroll 4
    for (int ci = 0; ci < 128; ci++) {
        const int br = ci >> 5;
        const int c  = ci & 31;
        const unsigned int eu =
            *(const unsigned int*)&g_E[(((size_t)br * B_ + b) * C_ + c) * HW_ + p];
        vf2 v = (vf2){__uint_as_float(eu << 16),
                      __uint_as_float(eu & 0xffff0000u)};
        const float sc = g_stats[ci], sh = g_stats[128 + ci];
        v = __builtin_elementwise_fma(v, (vf2){sc, sc}, (vf2){sh, sh});
        v = __builtin_elementwise_max(v, (vf2){0.f, 0.f});
        const float* wr = &g_Wt[ci * 32 + og * 16];
#pragma unroll
        for (int k = 0; k < 16; k++)
            acc[k] = __builtin_elementwise_fma(v, (vf2){wr[k], wr[k]}, acc[k]);
    }

    unsigned short* Yp = g_Yb + ((size_t)b * C_ + og * 16) * HW_ + p;
#pragma unroll
    for (int k = 0; k < 16; k++) {
        const unsigned int pack =
            (unsigned int)f2bf(acc[k].x) | ((unsigned int)f2bf(acc[k].y) << 16);
        *(unsigned int*)&Yp[(size_t)k * HW_] = pack;
    }

    // BN2 block partials for the 16 channels (from unrounded accs)
    __shared__ float l1[16][4], l2[16][4];
    const int lane = threadIdx.x & 63;
    const int wv   = threadIdx.x >> 6;
#pragma unroll
    for (int k = 0; k < 16; k++) {
        float s1 = acc[k].x + acc[k].y;
        float s2 = acc[k].x * acc[k].x + acc[k].y * acc[k].y;
#pragma unroll
        for (int off = 32; off >= 1; off >>= 1) {
            s1 += __shfl_down(s1, off, 64);
            s2 += __shfl_down(s2, off, 64);
        }
        if (lane == 0) { l1[k][wv] = s1; l2[k][wv] = s2; }
    }
    __syncthreads();
    if (threadIdx.x < 16) {
        const int k = threadIdx.x;
        const int chan = og * 16 + k;
        const int slot = chan * 288 + b * 72 + blockIdx.x;
        g_p2[slot]       = l1[k][0] + l1[k][1] + l1[k][2] + l1[k][3];
        g_p2[NP2 + slot] = l2[k][0] + l2[k][1] + l2[k][2] + l2[k][3];
    }
}

// ---------------------------------------------------------------------------
// final: inline BN2-finalize (reduce 288 partials for this block's channel)
// + BN2 + ReLU -> f32. 8 px/thread. grid (18, 32, 4)
// ---------------------------------------------------------------------------
__global__ __launch_bounds__(256) void final_k(const float* __restrict__ g,
                                               const float* __restrict__ bb,
                                               float* __restrict__ out) {
    const int c = blockIdx.y;
    const int b = blockIdx.z;

    __shared__ float l1[4], l2[4];
    __shared__ float sScSh[2];
    {
        const int base = c * 288;
        float s1 = 0.0f, s2 = 0.0f;
        for (int i = threadIdx.x; i < 288; i += 256) {
            s1 += g_p2[base + i];
            s2 += g_p2[NP2 + base + i];
        }
#pragma unroll
        for (int off = 32; off >= 1; off >>= 1) {
            s1 += __shfl_down(s1, off, 64);
            s2 += __shfl_down(s2, off, 64);
        }
        const int lane = threadIdx.x & 63;
        const int wv   = threadIdx.x >> 6;
        if (lane == 0) { l1[wv] = s1; l2[wv] = s2; }
        __syncthreads();
        if (threadIdx.x == 0) {
            const float S1 = l1[0] + l1[1] + l1[2] + l1[3];
            const float S2 = l2[0] + l2[1] + l2[2] + l2[3];
            const float N  = (float)(B_ * HW_);
            const float mu = S1 / N;
            const float va = fmaxf(S2 / N - mu * mu, 0.0f);
            const float sc = g[c] * rsqrtf(va + EPS_);
            sScSh[0] = sc;
            sScSh[1] = bb[c] - mu * sc;
        }
        __syncthreads();
    }
    const float sc = sScSh[0];
    const float sh = sScSh[1];

    const size_t base = (size_t)(b * C_ + c) * HW_ + (blockIdx.x * 256 + threadIdx.x) * 8;
    const uint4 u = *(const uint4*)&g_Yb[base];

    float4 r0, r1;
    r0.x = fmaxf(fmaf(__uint_as_float(u.x << 16),         sc, sh), 0.0f);
    r0.y = fmaxf(fmaf(__uint_as_float(u.x & 0xffff0000u), sc, sh), 0.0f);
    r0.z = fmaxf(fmaf(__uint_as_float(u.y << 16),         sc, sh), 0.0f);
    r0.w = fmaxf(fmaf(__uint_as_float(u.y & 0xffff0000u), sc, sh), 0.0f);
    r1.x = fmaxf(fmaf(__uint_as_float(u.z << 16),         sc, sh), 0.0f);
    r1.y = fmaxf(fmaf(__uint_as_float(u.z & 0xffff0000u), sc, sh), 0.0f);
    r1.z = fmaxf(fmaf(__uint_as_float(u.w << 16),         sc, sh), 0.0f);
    r1.w = fmaxf(fmaf(__uint_as_float(u.w & 0xffff0000u), sc, sh), 0.0f);

    *(float4*)&out[base]     = r0;
    *(float4*)&out[base + 4] = r1;
}

// ---------------------------------------------------------------------------
extern "C" void kernel_launch(void* const* d_in, const int* in_sizes, int n_in,
                              void* d_out, int out_size, void* d_ws, size_t ws_size,
                              hipStream_t stream) {
    const float* x  = (const float*)d_in[0];
    const float* wd = (const float*)d_in[1];
    const float* we = (const float*)d_in[2];
    const float* gs = (const float*)d_in[3];
    const float* bs = (const float*)d_in[4];
    const float* Wc = (const float*)d_in[5];
    const float* g  = (const float*)d_in[6];
    const float* bb = (const float*)d_in[7];

    prep_k<<<1, 256, 0, stream>>>(wd, we);
    morph_k<<<dim3(36, C_, B_), 256, 0, stream>>>(x);
    fin1_k<<<128, 256, 0, stream>>>(gs, bs, Wc);
    conv_k<<<dim3(HW_ / 512, 2, B_), 256, 0, stream>>>();
    final_k<<<dim3(HW_ / 2048, C_, B_), 256, 0, stream>>>(g, bb, (float*)d_out);
}

// Round 18
// 102.241 us; speedup vs baseline: 1.0525x; 1.0525x over previous
//
#include <hip/hip_runtime.h>
#include <hip/hip_bf16.h>

// Problem constants
#define B_   4
#define C_   32
#define H_   192
#define W_   192
#define HW_  (H_ * W_)          // 36864
#define EPS_ 1e-5f

#define SCALE_IN  21.640425613334453f   // beta/ln2
#define SCALE_OUT 0.046209812037329687f // ln2/beta

#define SPW 48                  // sP row stride
#define SQW 40                  // sQ row stride

#define NP1 (128 * 576)         // chan * (4 b * 36 tiles * 4 waves)
#define NP2 (32 * 288)          // chan * (4 b * 72 blocks)

typedef float vf2 __attribute__((ext_vector_type(2)));

// bf16 <-> f32 helpers (bit-exact shift load, RNE store)
__device__ __forceinline__ float bf2f(unsigned short u) {
    return __uint_as_float((unsigned int)u << 16);
}
__device__ __forceinline__ unsigned short f2bf(float f) {
    const unsigned int u = __float_as_uint(f);
    return (unsigned short)((u + 0x7fffu + ((u >> 16) & 1u)) >> 16);
}

// ---------------------------------------------------------------------------
// Scratch (module globals; no atomics anywhere).
//  g_cw[0..1151] = 2^(s*wd), [1152..2303] = 2^(s*we)   ((br*C+c)*9+tap)
//  g_Wt[ci*32+o] = Wc[o*128+ci]  (filled by fin1_k)
//  g_stats[0..127] sc1  [128..255] sh1
// ---------------------------------------------------------------------------
__device__ float          g_cw[2304];
__device__ float          g_Wt[4096];
__device__ float          g_stats[256];
__device__ float          g_p1[2 * NP1];
__device__ float          g_p2[2 * NP2];
__device__ __attribute__((aligned(16))) unsigned short g_E[(size_t)4 * B_ * C_ * HW_];  // 37.75 MB
__device__ __attribute__((aligned(16))) unsigned short g_Yb[(size_t)B_ * C_ * HW_];     // 9.44 MB

// ---------------------------------------------------------------------------
// prep: exponentiate morphology weights (wave-uniform s_loads in morph_k)
// ---------------------------------------------------------------------------
__global__ void prep_k(const float* __restrict__ wd, const float* __restrict__ we) {
    for (int i = threadIdx.x; i < 2304; i += 256) {
        const float v = (i < 1152) ? wd[i] : we[i - 1152];
        g_cw[i] = exp2f(SCALE_IN * v);
    }
}

// ---------------------------------------------------------------------------
// One morphology branch (dilate-recip + erode) on a staged 48x48 P tile.
// sP: P = 2^(s*x), halo +-8, out-of-image = 1.0. sQ: Q = 1/dilate-sum.
// 4 cells/thread, float4 LDS ops, all tap indices compile-time via D.
// INT: whole Q window in-image -> skip per-cell bounds select.
// ---------------------------------------------------------------------------
template<int D, bool INT>
__device__ __forceinline__ void morph_branch(int b, int c, int h0, int w0,
                                             int slotbase,
                                             const float* __restrict__ sP,
                                             float* __restrict__ sQ) {
    constexpr int QE    = 32 + 2 * D;
    constexpr int QEG   = (QE + 3) / 4;
    constexpr int UNITS = QE * QEG;
    constexpr int POFF  = 8 - 2 * D;
    constexpr int AB    = POFF & ~3;
    constexpr int OFF   = POFF & 3;
    constexpr int NR    = (OFF + 2 * D + 4 + 3) / 4;
    constexpr int NR3   = (2 * D + 4 + 3) / 4;
    constexpr int br    = D - 1;

    const int tid = threadIdx.x;
    const int cb  = (br * C_ + c) * 9;

    // ---- phase 2: Q = rcp( sum cd * P_taps ); out-of-image cells := 1 ----
    {
        float cd[9];
#pragma unroll
        for (int k = 0; k < 9; k++) cd[k] = g_cw[cb + k];

#pragma unroll
        for (int it = 0; it < 2; ++it) {
            const int unit = tid + it * 256;
            if (unit < UNITS) {
                const int qi = unit / QEG;
                const int qj = (unit - qi * QEG) * 4;
                float a0 = 0.f, a1 = 0.f, a2 = 0.f, a3 = 0.f;
#pragma unroll
                for (int i = 0; i < 3; i++) {
                    const float* rp = &sP[(qi + 8 + (i - 2) * D) * SPW + qj + AB];
                    float buf[NR * 4];
#pragma unroll
                    for (int r = 0; r < NR; r++)
                        *(float4*)&buf[r * 4] = *(const float4*)&rp[r * 4];
#pragma unroll
                    for (int j = 0; j < 3; j++) {
                        const float wgt = cd[i * 3 + j];
                        a0 = fmaf(wgt, buf[OFF + j * D + 0], a0);
                        a1 = fmaf(wgt, buf[OFF + j * D + 1], a1);
                        a2 = fmaf(wgt, buf[OFF + j * D + 2], a2);
                        a3 = fmaf(wgt, buf[OFF + j * D + 3], a3);
                    }
                }
                float q0 = __builtin_amdgcn_rcpf(a0);
                float q1 = __builtin_amdgcn_rcpf(a1);
                float q2 = __builtin_amdgcn_rcpf(a2);
                float q3 = __builtin_amdgcn_rcpf(a3);
                if constexpr (!INT) {
                    const int hq = h0 - D + qi;
                    const int wq = w0 - D + qj;
                    const bool rowo = (hq < 0) || (hq >= H_);
                    q0 = (rowo || (wq + 0 < 0) || (wq + 0 >= W_)) ? 1.0f : q0;
                    q1 = (rowo || (wq + 1 < 0) || (wq + 1 >= W_)) ? 1.0f : q1;
                    q2 = (rowo || (wq + 2 < 0) || (wq + 2 >= W_)) ? 1.0f : q2;
                    q3 = (rowo || (wq + 3 < 0) || (wq + 3 >= W_)) ? 1.0f : q3;
                }
                *(float4*)&sQ[qi * SQW + qj] = make_float4(q0, q1, q2, q3);
            }
        }
    }
    __syncthreads();

    // ---- phase 3: E = -(ln2/beta)*log2( sum ce * Q_taps ), 4 px/thread ----
    {
        float ce[9];
#pragma unroll
        for (int k = 0; k < 9; k++) ce[k] = g_cw[1152 + cb + k];

        const int oi = tid >> 3;
        const int oj = (tid & 7) * 4;
        float t0 = 0.f, t1 = 0.f, t2 = 0.f, t3 = 0.f;
#pragma unroll
        for (int i = 0; i < 3; i++) {
            const float* rq = &sQ[(oi + i * D) * SQW + oj];
            float buf[NR3 * 4];
#pragma unroll
            for (int r = 0; r < NR3; r++)
                *(float4*)&buf[r * 4] = *(const float4*)&rq[r * 4];
#pragma unroll
            for (int j = 0; j < 3; j++) {
                const float wgt = ce[i * 3 + j];
                t0 = fmaf(wgt, buf[j * D + 0], t0);
                t1 = fmaf(wgt, buf[j * D + 1], t1);
                t2 = fmaf(wgt, buf[j * D + 2], t2);
                t3 = fmaf(wgt, buf[j * D + 3], t3);
            }
        }
        const float e0 = -SCALE_OUT * log2f(t0);
        const float e1 = -SCALE_OUT * log2f(t1);
        const float e2 = -SCALE_OUT * log2f(t2);
        const float e3 = -SCALE_OUT * log2f(t3);

        ushort4 r4;
        r4.x = f2bf(e0); r4.y = f2bf(e1); r4.z = f2bf(e2); r4.w = f2bf(e3);
        *(ushort4*)&g_E[(((size_t)br * B_ + b) * C_ + c) * HW_
                        + (size_t)(h0 + oi) * W_ + w0 + oj] = r4;

        float s1 = e0 + e1 + e2 + e3;
        float s2 = e0 * e0 + e1 * e1 + e2 * e2 + e3 * e3;
#pragma unroll
        for (int off = 32; off >= 1; off >>= 1) {
            s1 += __shfl_down(s1, off, 64);
            s2 += __shfl_down(s2, off, 64);
        }
        if ((tid & 63) == 0) {
            const int slot = (br * C_ + c) * 576 + slotbase + (tid >> 6);
            g_p1[slot]       = s1;
            g_p1[NP1 + slot] = s2;
        }
    }
    __syncthreads();
}

// ---------------------------------------------------------------------------
// fused all-branch morphology. grid (36 tiles, 32 c, 4 b), 256 threads.
// Stage is vectorized (float4) for column-interior tiles (tw 1..4).
// ---------------------------------------------------------------------------
__global__ __launch_bounds__(256) void morph_k(const float* __restrict__ x) {
    __shared__ float sP[48 * SPW];
    __shared__ float sQ[40 * SQW];
    const int tile = blockIdx.x;
    const int c    = blockIdx.y;
    const int b    = blockIdx.z;
    const int th   = tile / 6;
    const int tw   = tile - th * 6;
    const int h0   = th * 32, w0 = tw * 32;

    const float* xm = x + (size_t)(b * C_ + c) * HW_;
    if (tw >= 1 && tw <= 4) {
        // fast path: all 48 columns in-image; only row range needs checking
#pragma unroll
        for (int pass = 0; pass < 3; ++pass) {
            const int u = threadIdx.x + pass * 256;
            if (u < 576) {
                const int r  = u / 12;
                const int q4 = (u - r * 12) * 4;
                const int ih = h0 - 8 + r;
                float4 v;
                if (ih >= 0 && ih < H_) {
                    const float4 xv = *(const float4*)&xm[ih * W_ + (w0 - 8 + q4)];
                    v.x = exp2f(SCALE_IN * xv.x);
                    v.y = exp2f(SCALE_IN * xv.y);
                    v.z = exp2f(SCALE_IN * xv.z);
                    v.w = exp2f(SCALE_IN * xv.w);
                } else {
                    v = make_float4(1.f, 1.f, 1.f, 1.f);
                }
                *(float4*)&sP[r * SPW + q4] = v;
            }
        }
    } else {
        // slow path: per-cell clamp + pad-select
        for (int idx = threadIdx.x; idx < 48 * 48; idx += 256) {
            const int r  = idx / 48, q = idx - r * 48;
            const int ih = h0 - 8 + r, iw = w0 - 8 + q;
            const int ihc = min(max(ih, 0), H_ - 1);
            const int iwc = min(max(iw, 0), W_ - 1);
            const float xv = xm[ihc * W_ + iwc];
            const bool inb = (ih == ihc) && (iw == iwc);
            sP[r * SPW + q] = inb ? exp2f(SCALE_IN * xv) : 1.0f;
        }
    }
    __syncthreads();

    const int slotbase = (b * 36 + tile) * 4;
    if (th >= 1 && th <= 4 && tw >= 1 && tw <= 4) {
        morph_branch<1, true>(b, c, h0, w0, slotbase, sP, sQ);
        morph_branch<2, true>(b, c, h0, w0, slotbase, sP, sQ);
        morph_branch<3, true>(b, c, h0, w0, slotbase, sP, sQ);
        morph_branch<4, true>(b, c, h0, w0, slotbase, sP, sQ);
    } else {
        morph_branch<1, false>(b, c, h0, w0, slotbase, sP, sQ);
        morph_branch<2, false>(b, c, h0, w0, slotbase, sP, sQ);
        morph_branch<3, false>(b, c, h0, w0, slotbase, sP, sQ);
        morph_branch<4, false>(b, c, h0, w0, slotbase, sP, sQ);
    }
}

// ---------------------------------------------------------------------------
// finalize BN1 (reduce 576 partials per channel) + Wc transpose. grid = 128
// ---------------------------------------------------------------------------
__global__ __launch_bounds__(256) void fin1_k(const float* __restrict__ gs,
                                              const float* __restrict__ bs,
                                              const float* __restrict__ Wc) {
    const int chan = blockIdx.x;          // input channel ci
    if (threadIdx.x < 32)
        g_Wt[chan * 32 + threadIdx.x] = Wc[(size_t)threadIdx.x * 128 + chan];

    const int base = chan * 576;
    float s1 = 0.0f, s2 = 0.0f;
    for (int i = threadIdx.x; i < 576; i += 256) {
        s1 += g_p1[base + i];
        s2 += g_p1[NP1 + base + i];
    }
#pragma unroll
    for (int off = 32; off >= 1; off >>= 1) {
        s1 += __shfl_down(s1, off, 64);
        s2 += __shfl_down(s2, off, 64);
    }
    __shared__ float l1[4], l2[4];
    const int lane = threadIdx.x & 63;
    const int wv   = threadIdx.x >> 6;
    if (lane == 0) { l1[wv] = s1; l2[wv] = s2; }
    __syncthreads();
    if (threadIdx.x == 0) {
        const float S1 = l1[0] + l1[1] + l1[2] + l1[3];
        const float S2 = l2[0] + l2[1] + l2[2] + l2[3];
        const float N  = (float)(B_ * HW_);
        const float mu = S1 / N;
        const float va = fmaxf(S2 / N - mu * mu, 0.0f);
        const float sc = gs[chan] * rsqrtf(va + EPS_);
        g_stats[chan]       = sc;
        g_stats[128 + chan] = bs[chan] - mu * sc;
    }
}

// ---------------------------------------------------------------------------
// fused BN1+ReLU + 1x1 conv + BN2 partials. grid (72, 4 og, 4 b).
// 2 pixels/thread as packed float2 lanes (v_pk_fma_f32); 8 outputs/thread.
// Weights/scales wave-uniform (scalar); Y stored bf16.
// ---------------------------------------------------------------------------
__global__ __launch_bounds__(256) void conv_k(void) {
    const int og = blockIdx.y;            // outputs og*8 .. og*8+7
    const int b  = blockIdx.z;
    const int p  = (blockIdx.x * 256 + threadIdx.x) * 2;

    vf2 acc[8];
#pragma unroll
    for (int k = 0; k < 8; k++) acc[k] = (vf2){0.f, 0.f};

#pragma unroll 8
    for (int ci = 0; ci < 128; ci++) {
        const int br = ci >> 5;
        const int c  = ci & 31;
        const unsigned int eu =
            *(const unsigned int*)&g_E[(((size_t)br * B_ + b) * C_ + c) * HW_ + p];
        vf2 v = (vf2){__uint_as_float(eu << 16),
                      __uint_as_float(eu & 0xffff0000u)};
        const float sc = g_stats[ci], sh = g_stats[128 + ci];
        v = __builtin_elementwise_fma(v, (vf2){sc, sc}, (vf2){sh, sh});
        v = __builtin_elementwise_max(v, (vf2){0.f, 0.f});
        const float* wr = &g_Wt[ci * 32 + og * 8];
#pragma unroll
        for (int k = 0; k < 8; k++)
            acc[k] = __builtin_elementwise_fma(v, (vf2){wr[k], wr[k]}, acc[k]);
    }

    unsigned short* Yp = g_Yb + ((size_t)b * C_ + og * 8) * HW_ + p;
#pragma unroll
    for (int k = 0; k < 8; k++) {
        const unsigned int pack =
            (unsigned int)f2bf(acc[k].x) | ((unsigned int)f2bf(acc[k].y) << 16);
        *(unsigned int*)&Yp[(size_t)k * HW_] = pack;
    }

    // BN2 block partials for the 8 channels (from unrounded accs)
    __shared__ float l1[8][4], l2[8][4];
    const int lane = threadIdx.x & 63;
    const int wv   = threadIdx.x >> 6;
#pragma unroll
    for (int k = 0; k < 8; k++) {
        float s1 = acc[k].x + acc[k].y;
        float s2 = acc[k].x * acc[k].x + acc[k].y * acc[k].y;
#pragma unroll
        for (int off = 32; off >= 1; off >>= 1) {
            s1 += __shfl_down(s1, off, 64);
            s2 += __shfl_down(s2, off, 64);
        }
        if (lane == 0) { l1[k][wv] = s1; l2[k][wv] = s2; }
    }
    __syncthreads();
    if (threadIdx.x < 8) {
        const int k = threadIdx.x;
        const int chan = og * 8 + k;
        const int slot = chan * 288 + b * 72 + blockIdx.x;
        g_p2[slot]       = l1[k][0] + l1[k][1] + l1[k][2] + l1[k][3];
        g_p2[NP2 + slot] = l2[k][0] + l2[k][1] + l2[k][2] + l2[k][3];
    }
}

// ---------------------------------------------------------------------------
// final: inline BN2-finalize (reduce 288 partials for this block's channel)
// + BN2 + ReLU -> f32. 8 px/thread. grid (18, 32, 4)
// ---------------------------------------------------------------------------
__global__ __launch_bounds__(256) void final_k(const float* __restrict__ g,
                                               const float* __restrict__ bb,
                                               float* __restrict__ out) {
    const int c = blockIdx.y;
    const int b = blockIdx.z;

    __shared__ float l1[4], l2[4];
    __shared__ float sScSh[2];
    {
        const int base = c * 288;
        float s1 = 0.0f, s2 = 0.0f;
        for (int i = threadIdx.x; i < 288; i += 256) {
            s1 += g_p2[base + i];
            s2 += g_p2[NP2 + base + i];
        }
#pragma unroll
        for (int off = 32; off >= 1; off >>= 1) {
            s1 += __shfl_down(s1, off, 64);
            s2 += __shfl_down(s2, off, 64);
        }
        const int lane = threadIdx.x & 63;
        const int wv   = threadIdx.x >> 6;
        if (lane == 0) { l1[wv] = s1; l2[wv] = s2; }
        __syncthreads();
        if (threadIdx.x == 0) {
            const float S1 = l1[0] + l1[1] + l1[2] + l1[3];
            const float S2 = l2[0] + l2[1] + l2[2] + l2[3];
            const float N  = (float)(B_ * HW_);
            const float mu = S1 / N;
            const float va = fmaxf(S2 / N - mu * mu, 0.0f);
            const float sc = g[c] * rsqrtf(va + EPS_);
            sScSh[0] = sc;
            sScSh[1] = bb[c] - mu * sc;
        }
        __syncthreads();
    }
    const float sc = sScSh[0];
    const float sh = sScSh[1];

    const size_t base = (size_t)(b * C_ + c) * HW_ + (blockIdx.x * 256 + threadIdx.x) * 8;
    const uint4 u = *(const uint4*)&g_Yb[base];

    float4 r0, r1;
    r0.x = fmaxf(fmaf(__uint_as_float(u.x << 16),         sc, sh), 0.0f);
    r0.y = fmaxf(fmaf(__uint_as_float(u.x & 0xffff0000u), sc, sh), 0.0f);
    r0.z = fmaxf(fmaf(__uint_as_float(u.y << 16),         sc, sh), 0.0f);
    r0.w = fmaxf(fmaf(__uint_as_float(u.y & 0xffff0000u), sc, sh), 0.0f);
    r1.x = fmaxf(fmaf(__uint_as_float(u.z << 16),         sc, sh), 0.0f);
    r1.y = fmaxf(fmaf(__uint_as_float(u.z & 0xffff0000u), sc, sh), 0.0f);
    r1.z = fmaxf(fmaf(__uint_as_float(u.w << 16),         sc, sh), 0.0f);
    r1.w = fmaxf(fmaf(__uint_as_float(u.w & 0xffff0000u), sc, sh), 0.0f);

    *(float4*)&out[base]     = r0;
    *(float4*)&out[base + 4] = r1;
}

// ---------------------------------------------------------------------------
extern "C" void kernel_launch(void* const* d_in, const int* in_sizes, int n_in,
                              void* d_out, int out_size, void* d_ws, size_t ws_size,
                              hipStream_t stream) {
    const float* x  = (const float*)d_in[0];
    const float* wd = (const float*)d_in[1];
    const float* we = (const float*)d_in[2];
    const float* gs = (const float*)d_in[3];
    const float* bs = (const float*)d_in[4];
    const float* Wc = (const float*)d_in[5];
    const float* g  = (const float*)d_in[6];
    const float* bb = (const float*)d_in[7];

    prep_k<<<1, 256, 0, stream>>>(wd, we);
    morph_k<<<dim3(36, C_, B_), 256, 0, stream>>>(x);
    fin1_k<<<128, 256, 0, stream>>>(gs, bs, Wc);
    conv_k<<<dim3(HW_ / 512, 4, B_), 256, 0, stream>>>();
    final_k<<<dim3(HW_ / 2048, C_, B_), 256, 0, stream>>>(g, bb, (float*)d_out);
}

// Round 19
// 99.913 us; speedup vs baseline: 1.0770x; 1.0233x over previous
//
#include <hip/hip_runtime.h>
#include <hip/hip_bf16.h>

// Problem constants
#define B_   4
#define C_   32
#define H_   192
#define W_   192
#define HW_  (H_ * W_)          // 36864
#define EPS_ 1e-5f

#define SCALE_IN  21.640425613334453f   // beta/ln2
#define SCALE_OUT 0.046209812037329687f // ln2/beta

#define SPW 48                  // sP row stride
#define SQW 40                  // sQ row stride

#define NP1 (128 * 576)         // chan * (4 b * 36 tiles * 4 waves)
#define NP2 (32 * 288)          // chan * (4 b * 72 blocks)

// bf16 <-> f32 helpers (bit-exact shift load, RNE store)
__device__ __forceinline__ float bf2f(unsigned short u) {
    return __uint_as_float((unsigned int)u << 16);
}
__device__ __forceinline__ unsigned short f2bf(float f) {
    const unsigned int u = __float_as_uint(f);
    return (unsigned short)((u + 0x7fffu + ((u >> 16) & 1u)) >> 16);
}

// ---------------------------------------------------------------------------
// Scratch (module globals; no atomics anywhere).
//  g_cw[0..1151] = 2^(s*wd), [1152..2303] = 2^(s*we)   ((br*C+c)*9+tap)
//  g_Wt[ci*32+o] = Wc[o*128+ci]  (filled by fin1_k)
//  g_stats[0..127] sc1  [128..255] sh1
// ---------------------------------------------------------------------------
__device__ float          g_cw[2304];
__device__ float          g_Wt[4096];
__device__ float          g_stats[256];
__device__ float          g_p1[2 * NP1];
__device__ float          g_p2[2 * NP2];
__device__ __attribute__((aligned(16))) unsigned short g_E[(size_t)4 * B_ * C_ * HW_];  // 37.75 MB
__device__ __attribute__((aligned(16))) unsigned short g_Yb[(size_t)B_ * C_ * HW_];     // 9.44 MB

// ---------------------------------------------------------------------------
// prep: exponentiate morphology weights. grid = 9 blocks x 256 (one pass)
// ---------------------------------------------------------------------------
__global__ void prep_k(const float* __restrict__ wd, const float* __restrict__ we) {
    const int i = blockIdx.x * 256 + threadIdx.x;
    if (i < 2304) {
        const float v = (i < 1152) ? wd[i] : we[i - 1152];
        g_cw[i] = exp2f(SCALE_IN * v);
    }
}

// ---------------------------------------------------------------------------
// One morphology branch (dilate-recip + erode) on a staged 48x48 P tile.
// sP: P = 2^(s*x), halo +-8, out-of-image = 1.0. sQ: Q = 1/dilate-sum.
// 4 cells/thread, float4 LDS ops, all tap indices compile-time via D.
// INT: whole Q window in-image -> skip per-cell bounds select.
// ---------------------------------------------------------------------------
template<int D, bool INT>
__device__ __forceinline__ void morph_branch(int b, int c, int h0, int w0,
                                             int slotbase,
                                             const float* __restrict__ sP,
                                             float* __restrict__ sQ) {
    constexpr int QE    = 32 + 2 * D;
    constexpr int QEG   = (QE + 3) / 4;
    constexpr int UNITS = QE * QEG;
    constexpr int POFF  = 8 - 2 * D;
    constexpr int AB    = POFF & ~3;
    constexpr int OFF   = POFF & 3;
    constexpr int NR    = (OFF + 2 * D + 4 + 3) / 4;
    constexpr int NR3   = (2 * D + 4 + 3) / 4;
    constexpr int br    = D - 1;

    const int tid = threadIdx.x;
    const int cb  = (br * C_ + c) * 9;

    // ---- phase 2: Q = rcp( sum cd * P_taps ); out-of-image cells := 1 ----
    {
        float cd[9];
#pragma unroll
        for (int k = 0; k < 9; k++) cd[k] = g_cw[cb + k];

#pragma unroll
        for (int it = 0; it < 2; ++it) {
            const int unit = tid + it * 256;
            if (unit < UNITS) {
                const int qi = unit / QEG;
                const int qj = (unit - qi * QEG) * 4;
                float a0 = 0.f, a1 = 0.f, a2 = 0.f, a3 = 0.f;
#pragma unroll
                for (int i = 0; i < 3; i++) {
                    const float* rp = &sP[(qi + 8 + (i - 2) * D) * SPW + qj + AB];
                    float buf[NR * 4];
#pragma unroll
                    for (int r = 0; r < NR; r++)
                        *(float4*)&buf[r * 4] = *(const float4*)&rp[r * 4];
#pragma unroll
                    for (int j = 0; j < 3; j++) {
                        const float wgt = cd[i * 3 + j];
                        a0 = fmaf(wgt, buf[OFF + j * D + 0], a0);
                        a1 = fmaf(wgt, buf[OFF + j * D + 1], a1);
                        a2 = fmaf(wgt, buf[OFF + j * D + 2], a2);
                        a3 = fmaf(wgt, buf[OFF + j * D + 3], a3);
                    }
                }
                float q0 = __builtin_amdgcn_rcpf(a0);
                float q1 = __builtin_amdgcn_rcpf(a1);
                float q2 = __builtin_amdgcn_rcpf(a2);
                float q3 = __builtin_amdgcn_rcpf(a3);
                if constexpr (!INT) {
                    const int hq = h0 - D + qi;
                    const int wq = w0 - D + qj;
                    const bool rowo = (hq < 0) || (hq >= H_);
                    q0 = (rowo || (wq + 0 < 0) || (wq + 0 >= W_)) ? 1.0f : q0;
                    q1 = (rowo || (wq + 1 < 0) || (wq + 1 >= W_)) ? 1.0f : q1;
                    q2 = (rowo || (wq + 2 < 0) || (wq + 2 >= W_)) ? 1.0f : q2;
                    q3 = (rowo || (wq + 3 < 0) || (wq + 3 >= W_)) ? 1.0f : q3;
                }
                *(float4*)&sQ[qi * SQW + qj] = make_float4(q0, q1, q2, q3);
            }
        }
    }
    __syncthreads();

    // ---- phase 3: E = -(ln2/beta)*log2( sum ce * Q_taps ), 4 px/thread ----
    {
        float ce[9];
#pragma unroll
        for (int k = 0; k < 9; k++) ce[k] = g_cw[1152 + cb + k];

        const int oi = tid >> 3;
        const int oj = (tid & 7) * 4;
        float t0 = 0.f, t1 = 0.f, t2 = 0.f, t3 = 0.f;
#pragma unroll
        for (int i = 0; i < 3; i++) {
            const float* rq = &sQ[(oi + i * D) * SQW + oj];
            float buf[NR3 * 4];
#pragma unroll
            for (int r = 0; r < NR3; r++)
                *(float4*)&buf[r * 4] = *(const float4*)&rq[r * 4];
#pragma unroll
            for (int j = 0; j < 3; j++) {
                const float wgt = ce[i * 3 + j];
                t0 = fmaf(wgt, buf[j * D + 0], t0);
                t1 = fmaf(wgt, buf[j * D + 1], t1);
                t2 = fmaf(wgt, buf[j * D + 2], t2);
                t3 = fmaf(wgt, buf[j * D + 3], t3);
            }
        }
        const float e0 = -SCALE_OUT * log2f(t0);
        const float e1 = -SCALE_OUT * log2f(t1);
        const float e2 = -SCALE_OUT * log2f(t2);
        const float e3 = -SCALE_OUT * log2f(t3);

        ushort4 r4;
        r4.x = f2bf(e0); r4.y = f2bf(e1); r4.z = f2bf(e2); r4.w = f2bf(e3);
        *(ushort4*)&g_E[(((size_t)br * B_ + b) * C_ + c) * HW_
                        + (size_t)(h0 + oi) * W_ + w0 + oj] = r4;

        float s1 = e0 + e1 + e2 + e3;
        float s2 = e0 * e0 + e1 * e1 + e2 * e2 + e3 * e3;
#pragma unroll
        for (int off = 32; off >= 1; off >>= 1) {
            s1 += __shfl_down(s1, off, 64);
            s2 += __shfl_down(s2, off, 64);
        }
        if ((tid & 63) == 0) {
            const int slot = (br * C_ + c) * 576 + slotbase + (tid >> 6);
            g_p1[slot]       = s1;
            g_p1[NP1 + slot] = s2;
        }
    }
    __syncthreads();
}

// ---------------------------------------------------------------------------
// fused all-branch morphology. grid (36 tiles, 32 c, 4 b), 256 threads.
// Stage is vectorized (float4) for column-interior tiles (tw 1..4).
// ---------------------------------------------------------------------------
__global__ __launch_bounds__(256) void morph_k(const float* __restrict__ x) {
    __shared__ float sP[48 * SPW];
    __shared__ float sQ[40 * SQW];
    const int tile = blockIdx.x;
    const int c    = blockIdx.y;
    const int b    = blockIdx.z;
    const int th   = tile / 6;
    const int tw   = tile - th * 6;
    const int h0   = th * 32, w0 = tw * 32;

    const float* xm = x + (size_t)(b * C_ + c) * HW_;
    if (tw >= 1 && tw <= 4) {
        // fast path: all 48 columns in-image; only row range needs checking
#pragma unroll
        for (int pass = 0; pass < 3; ++pass) {
            const int u = threadIdx.x + pass * 256;
            if (u < 576) {
                const int r  = u / 12;
                const int q4 = (u - r * 12) * 4;
                const int ih = h0 - 8 + r;
                float4 v;
                if (ih >= 0 && ih < H_) {
                    const float4 xv = *(const float4*)&xm[ih * W_ + (w0 - 8 + q4)];
                    v.x = exp2f(SCALE_IN * xv.x);
                    v.y = exp2f(SCALE_IN * xv.y);
                    v.z = exp2f(SCALE_IN * xv.z);
                    v.w = exp2f(SCALE_IN * xv.w);
                } else {
                    v = make_float4(1.f, 1.f, 1.f, 1.f);
                }
                *(float4*)&sP[r * SPW + q4] = v;
            }
        }
    } else {
        // slow path: per-cell clamp + pad-select
        for (int idx = threadIdx.x; idx < 48 * 48; idx += 256) {
            const int r  = idx / 48, q = idx - r * 48;
            const int ih = h0 - 8 + r, iw = w0 - 8 + q;
            const int ihc = min(max(ih, 0), H_ - 1);
            const int iwc = min(max(iw, 0), W_ - 1);
            const float xv = xm[ihc * W_ + iwc];
            const bool inb = (ih == ihc) && (iw == iwc);
            sP[r * SPW + q] = inb ? exp2f(SCALE_IN * xv) : 1.0f;
        }
    }
    __syncthreads();

    const int slotbase = (b * 36 + tile) * 4;
    if (th >= 1 && th <= 4 && tw >= 1 && tw <= 4) {
        morph_branch<1, true>(b, c, h0, w0, slotbase, sP, sQ);
        morph_branch<2, true>(b, c, h0, w0, slotbase, sP, sQ);
        morph_branch<3, true>(b, c, h0, w0, slotbase, sP, sQ);
        morph_branch<4, true>(b, c, h0, w0, slotbase, sP, sQ);
    } else {
        morph_branch<1, false>(b, c, h0, w0, slotbase, sP, sQ);
        morph_branch<2, false>(b, c, h0, w0, slotbase, sP, sQ);
        morph_branch<3, false>(b, c, h0, w0, slotbase, sP, sQ);
        morph_branch<4, false>(b, c, h0, w0, slotbase, sP, sQ);
    }
}

// ---------------------------------------------------------------------------
// finalize BN1 (reduce 576 partials per channel) + Wc transpose. grid = 128
// ---------------------------------------------------------------------------
__global__ __launch_bounds__(256) void fin1_k(const float* __restrict__ gs,
                                              const float* __restrict__ bs,
                                              const float* __restrict__ Wc) {
    const int chan = blockIdx.x;          // input channel ci
    if (threadIdx.x < 32)
        g_Wt[chan * 32 + threadIdx.x] = Wc[(size_t)threadIdx.x * 128 + chan];

    const int base = chan * 576;
    float s1 = 0.0f, s2 = 0.0f;
    for (int i = threadIdx.x; i < 576; i += 256) {
        s1 += g_p1[base + i];
        s2 += g_p1[NP1 + base + i];
    }
#pragma unroll
    for (int off = 32; off >= 1; off >>= 1) {
        s1 += __shfl_down(s1, off, 64);
        s2 += __shfl_down(s2, off, 64);
    }
    __shared__ float l1[4], l2[4];
    const int lane = threadIdx.x & 63;
    const int wv   = threadIdx.x >> 6;
    if (lane == 0) { l1[wv] = s1; l2[wv] = s2; }
    __syncthreads();
    if (threadIdx.x == 0) {
        const float S1 = l1[0] + l1[1] + l1[2] + l1[3];
        const float S2 = l2[0] + l2[1] + l2[2] + l2[3];
        const float N  = (float)(B_ * HW_);
        const float mu = S1 / N;
        const float va = fmaxf(S2 / N - mu * mu, 0.0f);
        const float sc = gs[chan] * rsqrtf(va + EPS_);
        g_stats[chan]       = sc;
        g_stats[128 + chan] = bs[chan] - mu * sc;
    }
}

// ---------------------------------------------------------------------------
// fused BN1+ReLU + 1x1 conv + BN2 partials. grid (72, 4 og, 4 b).
// 2 pixels/thread; weights/scales wave-uniform (scalar); Y stored bf16.
// ---------------------------------------------------------------------------
__global__ __launch_bounds__(256) void conv_k(void) {
    const int og = blockIdx.y;
    const int b  = blockIdx.z;
    const int p  = (blockIdx.x * 256 + threadIdx.x) * 2;

    float acc0[8], acc1[8];
#pragma unroll
    for (int k = 0; k < 8; k++) { acc0[k] = 0.0f; acc1[k] = 0.0f; }

#pragma unroll 8
    for (int ci = 0; ci < 128; ci++) {
        const int br = ci >> 5;
        const int c  = ci & 31;
        const unsigned int eu =
            *(const unsigned int*)&g_E[(((size_t)br * B_ + b) * C_ + c) * HW_ + p];
        float v0 = __uint_as_float(eu << 16);
        float v1 = __uint_as_float(eu & 0xffff0000u);
        const float sc = g_stats[ci], sh = g_stats[128 + ci];
        v0 = fmaxf(fmaf(v0, sc, sh), 0.0f);
        v1 = fmaxf(fmaf(v1, sc, sh), 0.0f);
        const float* wr = &g_Wt[ci * 32 + og * 8];
#pragma unroll
        for (int k = 0; k < 8; k++) {
            acc0[k] = fmaf(v0, wr[k], acc0[k]);
            acc1[k] = fmaf(v1, wr[k], acc1[k]);
        }
    }

    unsigned short* Yp = g_Yb + ((size_t)b * C_ + og * 8) * HW_ + p;
#pragma unroll
    for (int k = 0; k < 8; k++) {
        const unsigned int pack =
            (unsigned int)f2bf(acc0[k]) | ((unsigned int)f2bf(acc1[k]) << 16);
        *(unsigned int*)&Yp[(size_t)k * HW_] = pack;
    }

    __shared__ float l1[8][4], l2[8][4];
    const int lane = threadIdx.x & 63;
    const int wv   = threadIdx.x >> 6;
#pragma unroll
    for (int k = 0; k < 8; k++) {
        float s1 = acc0[k] + acc1[k];
        float s2 = acc0[k] * acc0[k] + acc1[k] * acc1[k];
#pragma unroll
        for (int off = 32; off >= 1; off >>= 1) {
            s1 += __shfl_down(s1, off, 64);
            s2 += __shfl_down(s2, off, 64);
        }
        if (lane == 0) { l1[k][wv] = s1; l2[k][wv] = s2; }
    }
    __syncthreads();
    if (threadIdx.x < 8) {
        const int k = threadIdx.x;
        const int chan = og * 8 + k;
        const int slot = chan * 288 + b * 72 + blockIdx.x;
        g_p2[slot]       = l1[k][0] + l1[k][1] + l1[k][2] + l1[k][3];
        g_p2[NP2 + slot] = l2[k][0] + l2[k][1] + l2[k][2] + l2[k][3];
    }
}

// ---------------------------------------------------------------------------
// final: inline BN2-finalize (reduce 288 partials for this block's channel)
// + BN2 + ReLU -> f32. 8 px/thread. grid (18, 32, 4)
// ---------------------------------------------------------------------------
__global__ __launch_bounds__(256) void final_k(const float* __restrict__ g,
                                               const float* __restrict__ bb,
                                               float* __restrict__ out) {
    const int c = blockIdx.y;
    const int b = blockIdx.z;

    __shared__ float l1[4], l2[4];
    __shared__ float sScSh[2];
    {
        const int base = c * 288;
        float s1 = 0.0f, s2 = 0.0f;
        for (int i = threadIdx.x; i < 288; i += 256) {
            s1 += g_p2[base + i];
            s2 += g_p2[NP2 + base + i];
        }
#pragma unroll
        for (int off = 32; off >= 1; off >>= 1) {
            s1 += __shfl_down(s1, off, 64);
            s2 += __shfl_down(s2, off, 64);
        }
        const int lane = threadIdx.x & 63;
        const int wv   = threadIdx.x >> 6;
        if (lane == 0) { l1[wv] = s1; l2[wv] = s2; }
        __syncthreads();
        if (threadIdx.x == 0) {
            const float S1 = l1[0] + l1[1] + l1[2] + l1[3];
            const float S2 = l2[0] + l2[1] + l2[2] + l2[3];
            const float N  = (float)(B_ * HW_);
            const float mu = S1 / N;
            const float va = fmaxf(S2 / N - mu * mu, 0.0f);
            const float sc = g[c] * rsqrtf(va + EPS_);
            sScSh[0] = sc;
            sScSh[1] = bb[c] - mu * sc;
        }
        __syncthreads();
    }
    const float sc = sScSh[0];
    const float sh = sScSh[1];

    const size_t base = (size_t)(b * C_ + c) * HW_ + (blockIdx.x * 256 + threadIdx.x) * 8;
    const uint4 u = *(const uint4*)&g_Yb[base];

    float4 r0, r1;
    r0.x = fmaxf(fmaf(__uint_as_float(u.x << 16),         sc, sh), 0.0f);
    r0.y = fmaxf(fmaf(__uint_as_float(u.x & 0xffff0000u), sc, sh), 0.0f);
    r0.z = fmaxf(fmaf(__uint_as_float(u.y << 16),         sc, sh), 0.0f);
    r0.w = fmaxf(fmaf(__uint_as_float(u.y & 0xffff0000u), sc, sh), 0.0f);
    r1.x = fmaxf(fmaf(__uint_as_float(u.z << 16),         sc, sh), 0.0f);
    r1.y = fmaxf(fmaf(__uint_as_float(u.z & 0xffff0000u), sc, sh), 0.0f);
    r1.z = fmaxf(fmaf(__uint_as_float(u.w << 16),         sc, sh), 0.0f);
    r1.w = fmaxf(fmaf(__uint_as_float(u.w & 0xffff0000u), sc, sh), 0.0f);

    *(float4*)&out[base]     = r0;
    *(float4*)&out[base + 4] = r1;
}

// ---------------------------------------------------------------------------
extern "C" void kernel_launch(void* const* d_in, const int* in_sizes, int n_in,
                              void* d_out, int out_size, void* d_ws, size_t ws_size,
                              hipStream_t stream) {
    const float* x  = (const float*)d_in[0];
    const float* wd = (const float*)d_in[1];
    const float* we = (const float*)d_in[2];
    const float* gs = (const float*)d_in[3];
    const float* bs = (const float*)d_in[4];
    const float* Wc = (const float*)d_in[5];
    const float* g  = (const float*)d_in[6];
    const float* bb = (const float*)d_in[7];

    prep_k<<<9, 256, 0, stream>>>(wd, we);
    morph_k<<<dim3(36, C_, B_), 256, 0, stream>>>(x);
    fin1_k<<<128, 256, 0, stream>>>(gs, bs, Wc);
    conv_k<<<dim3(HW_ / 512, 4, B_), 256, 0, stream>>>();
    final_k<<<dim3(HW_ / 2048, C_, B_), 256, 0, stream>>>(g, bb, (float*)d_out);
}